// Round 2
// baseline (2379.109 us; speedup 1.0000x reference)
//
#include <hip/hip_runtime.h>
#include <hip/hip_bf16.h>

#define HC 256      // H*C == IN
#define DHID 1024
#define NEG 0.2f
#define LN_EPS 1e-5f

typedef unsigned short u16;
typedef unsigned int u32;

__device__ __forceinline__ float bf2f(u16 u) {
  union { u32 i; float f; } v; v.i = ((u32)u) << 16; return v.f;
}
__device__ __forceinline__ u16 f2bf(float f) {
  union { float f; u32 i; } v; v.f = f;
  u32 r = v.i + 0x7fffu + ((v.i >> 16) & 1u);
  return (u16)(r >> 16);
}

// ---------------- GEMM 1: out_bf16 = A(f32)[M,K] @ B(f32)[K,NB] + bias ----------------
__global__ __launch_bounds__(256) void gemm_xw_bf16(
    const float* __restrict__ A, const float* __restrict__ B,
    const float* __restrict__ bias, u16* __restrict__ out,
    int M, int K, int NB)
{
  __shared__ float As[16][64];
  __shared__ float Bs[16][64];
  const int tid = threadIdx.x;
  const int tx = tid & 15, ty = tid >> 4;
  const int rowBase = blockIdx.x * 64;
  const int colBase = blockIdx.y * 64;
  const int la_r = tid >> 2, la_k = (tid & 3) << 2;
  const int lb_k = tid >> 4, lb_c = (tid & 15) << 2;
  float acc[4][4] = {};
  for (int k0 = 0; k0 < K; k0 += 16) {
    int ar = rowBase + la_r;
    float4 av = make_float4(0.f, 0.f, 0.f, 0.f);
    if (ar < M) av = *(const float4*)&A[(size_t)ar * K + k0 + la_k];
    As[la_k + 0][la_r] = av.x; As[la_k + 1][la_r] = av.y;
    As[la_k + 2][la_r] = av.z; As[la_k + 3][la_r] = av.w;
    *(float4*)&Bs[lb_k][lb_c] = *(const float4*)&B[(size_t)(k0 + lb_k) * NB + colBase + lb_c];
    __syncthreads();
#pragma unroll
    for (int k = 0; k < 16; ++k) {
      float a_[4], b_[4];
      *(float4*)a_ = *(const float4*)&As[k][ty << 2];
      *(float4*)b_ = *(const float4*)&Bs[k][tx << 2];
#pragma unroll
      for (int i = 0; i < 4; ++i)
#pragma unroll
        for (int j = 0; j < 4; ++j)
          acc[i][j] = fmaf(a_[i], b_[j], acc[i][j]);
    }
    __syncthreads();
  }
#pragma unroll
  for (int i = 0; i < 4; ++i) {
    int r = rowBase + (ty << 2) + i;
    if (r >= M) continue;
#pragma unroll
    for (int j = 0; j < 4; ++j) {
      int c = colBase + (tx << 2) + j;
      out[(size_t)r * NB + c] = f2bf(acc[i][j] + bias[c]);
    }
  }
}

// ---------------- GEMM 2: h2 = relu( (y*A1+B1) @ W2 + b2 ), bf16 out ----------------
__global__ __launch_bounds__(256) void gemm_h1w2(
    const float* __restrict__ Y, const float* __restrict__ A1c, const float* __restrict__ B1c,
    const float* __restrict__ B, const float* __restrict__ bias,
    u16* __restrict__ out, int M, int K, int NB)
{
  __shared__ float As[16][64];
  __shared__ float Bs[16][64];
  const int tid = threadIdx.x;
  const int tx = tid & 15, ty = tid >> 4;
  const int rowBase = blockIdx.x * 64;
  const int colBase = blockIdx.y * 64;
  const int la_r = tid >> 2, la_k = (tid & 3) << 2;
  const int lb_k = tid >> 4, lb_c = (tid & 15) << 2;
  float acc[4][4] = {};
  for (int k0 = 0; k0 < K; k0 += 16) {
    int ar = rowBase + la_r;
    float4 av = make_float4(0.f, 0.f, 0.f, 0.f);
    if (ar < M) {
      float4 yv = *(const float4*)&Y[(size_t)ar * K + k0 + la_k];
      float4 aa = *(const float4*)&A1c[k0 + la_k];
      float4 bb = *(const float4*)&B1c[k0 + la_k];
      av.x = fmaf(yv.x, aa.x, bb.x);
      av.y = fmaf(yv.y, aa.y, bb.y);
      av.z = fmaf(yv.z, aa.z, bb.z);
      av.w = fmaf(yv.w, aa.w, bb.w);
    }
    As[la_k + 0][la_r] = av.x; As[la_k + 1][la_r] = av.y;
    As[la_k + 2][la_r] = av.z; As[la_k + 3][la_r] = av.w;
    *(float4*)&Bs[lb_k][lb_c] = *(const float4*)&B[(size_t)(k0 + lb_k) * NB + colBase + lb_c];
    __syncthreads();
#pragma unroll
    for (int k = 0; k < 16; ++k) {
      float a_[4], b_[4];
      *(float4*)a_ = *(const float4*)&As[k][ty << 2];
      *(float4*)b_ = *(const float4*)&Bs[k][tx << 2];
#pragma unroll
      for (int i = 0; i < 4; ++i)
#pragma unroll
        for (int j = 0; j < 4; ++j)
          acc[i][j] = fmaf(a_[i], b_[j], acc[i][j]);
    }
    __syncthreads();
  }
#pragma unroll
  for (int i = 0; i < 4; ++i) {
    int r = rowBase + (ty << 2) + i;
    if (r >= M) continue;
#pragma unroll
    for (int j = 0; j < 4; ++j) {
      int c = colBase + (tx << 2) + j;
      float v = acc[i][j] + bias[c];
      v = fmaxf(v, 0.f);
      out[(size_t)r * NB + c] = f2bf(v);
    }
  }
}

// ---------------- GEMM 3: z(f32) = h2(bf16)[M,K] @ W3 + b3, + LN stats ----------------
__global__ __launch_bounds__(256) void gemm_h2w3(
    const u16* __restrict__ A, const float* __restrict__ B,
    const float* __restrict__ bias, float* __restrict__ out,
    double* __restrict__ stats, int M, int K, int NB)
{
  __shared__ float As[16][64];
  __shared__ float Bs[16][64];
  const int tid = threadIdx.x;
  const int tx = tid & 15, ty = tid >> 4;
  const int rowBase = blockIdx.x * 64;
  const int colBase = blockIdx.y * 64;
  const int la_r = tid >> 2, la_k = (tid & 3) << 2;
  const int lb_k = tid >> 4, lb_c = (tid & 15) << 2;
  float acc[4][4] = {};
  for (int k0 = 0; k0 < K; k0 += 16) {
    int ar = rowBase + la_r;
    float a0 = 0.f, a1 = 0.f, a2 = 0.f, a3 = 0.f;
    if (ar < M) {
      ushort4 u = *(const ushort4*)&A[(size_t)ar * K + k0 + la_k];
      a0 = bf2f(u.x); a1 = bf2f(u.y); a2 = bf2f(u.z); a3 = bf2f(u.w);
    }
    As[la_k + 0][la_r] = a0; As[la_k + 1][la_r] = a1;
    As[la_k + 2][la_r] = a2; As[la_k + 3][la_r] = a3;
    *(float4*)&Bs[lb_k][lb_c] = *(const float4*)&B[(size_t)(k0 + lb_k) * NB + colBase + lb_c];
    __syncthreads();
#pragma unroll
    for (int k = 0; k < 16; ++k) {
      float a_[4], b_[4];
      *(float4*)a_ = *(const float4*)&As[k][ty << 2];
      *(float4*)b_ = *(const float4*)&Bs[k][tx << 2];
#pragma unroll
      for (int i = 0; i < 4; ++i)
#pragma unroll
        for (int j = 0; j < 4; ++j)
          acc[i][j] = fmaf(a_[i], b_[j], acc[i][j]);
    }
    __syncthreads();
  }
  float s1 = 0.f, s2 = 0.f;
#pragma unroll
  for (int i = 0; i < 4; ++i) {
    int r = rowBase + (ty << 2) + i;
    if (r >= M) continue;
#pragma unroll
    for (int j = 0; j < 4; ++j) {
      int c = colBase + (tx << 2) + j;
      float v = acc[i][j] + bias[c];
      out[(size_t)r * NB + c] = v;
      s1 += v;
      s2 += v * v;
    }
  }
  // wave-level reduction of LN stats
#pragma unroll
  for (int d = 1; d < 64; d <<= 1) {
    s1 += __shfl_xor(s1, d);
    s2 += __shfl_xor(s2, d);
  }
  if ((threadIdx.x & 63) == 0) {
    atomicAdd(&stats[0], (double)s1);
    atomicAdd(&stats[1], (double)s2);
  }
}

// ---------------- CSR build ----------------
__global__ void deg_count(const int* __restrict__ dst, int* __restrict__ deg, int E) {
  int i = blockIdx.x * blockDim.x + threadIdx.x;
  if (i < E) atomicAdd(&deg[dst[i]], 1);
}

__global__ __launch_bounds__(1024) void scan_k(const int* __restrict__ deg, int* __restrict__ off, int n) {
  __shared__ int wsum[16];
  __shared__ int carrySh;
  const int tid = threadIdx.x, lane = tid & 63, w = tid >> 6;
  if (tid == 0) carrySh = 0;
  __syncthreads();
  for (int base = 0; base < n; base += 1024) {
    int i = base + tid;
    int v = (i < n) ? deg[i] : 0;
    int incl = v;
#pragma unroll
    for (int d = 1; d < 64; d <<= 1) {
      int t = __shfl_up(incl, d);
      if (lane >= d) incl += t;
    }
    if (lane == 63) wsum[w] = incl;
    __syncthreads();
    int waveOff = 0, total = 0;
#pragma unroll
    for (int k = 0; k < 16; ++k) {
      int s = wsum[k];
      if (k < w) waveOff += s;
      total += s;
    }
    int carry = carrySh;
    if (i < n) off[i] = carry + waveOff + incl - v;
    __syncthreads();
    if (tid == 0) carrySh = carry + total;
    __syncthreads();
  }
  if (threadIdx.x == 0) off[n] = carrySh;
}

__global__ void fill_csr(const int* __restrict__ src, const int* __restrict__ dst,
                         const int* __restrict__ off, int* __restrict__ cur,
                         int* __restrict__ csr, int E) {
  int i = blockIdx.x * blockDim.x + threadIdx.x;
  if (i < E) {
    int d = dst[i];
    int pos = off[d] + atomicAdd(&cur[d], 1);
    csr[pos] = src[i];
  }
}

// ---------------- fused GATv2 edge-softmax-aggregate: one wave per node ----------------
// 8-edge chunked: 8 independent gathers in flight, then one batched
// online-softmax update (single rescale + 8 weighted accumulates).
__global__ __launch_bounds__(256) void gat_agg(
    const u16* __restrict__ xl, const u16* __restrict__ xr,
    const float* __restrict__ x, const int* __restrict__ off,
    const int* __restrict__ csr, const float* __restrict__ att,
    const float* __restrict__ b_gat, float* __restrict__ y,
    double* __restrict__ stats, int N)
{
  const int lane = threadIdx.x & 63;
  const int node = blockIdx.x * 4 + (threadIdx.x >> 6);
  if (node >= N) return;
  const int v0 = lane << 2;   // this lane's 4 feature slots; head = lane>>3
  float attv[4];
  *(float4*)attv = *(const float4*)&att[v0];
  float xrv[4];
  {
    ushort4 u = *(const ushort4*)&xr[(size_t)node * HC + v0];
    xrv[0] = bf2f(u.x); xrv[1] = bf2f(u.y); xrv[2] = bf2f(u.z); xrv[3] = bf2f(u.w);
  }
  // self-loop initializes the online softmax state
  float m_run, d_run = 1.f;
  float agg[4];
  {
    ushort4 u = *(const ushort4*)&xl[(size_t)node * HC + v0];
    float xlv[4] = {bf2f(u.x), bf2f(u.y), bf2f(u.z), bf2f(u.w)};
    float part = 0.f;
#pragma unroll
    for (int m = 0; m < 4; ++m) {
      float s = xlv[m] + xrv[m];
      s = (s > 0.f) ? s : NEG * s;
      part = fmaf(attv[m], s, part);
    }
    part += __shfl_xor(part, 1);
    part += __shfl_xor(part, 2);
    part += __shfl_xor(part, 4);
    m_run = part;
#pragma unroll
    for (int m = 0; m < 4; ++m) agg[m] = xlv[m];
  }
  const int beg = off[node];
  const int cntE = off[node + 1] - beg;
  for (int e0 = 0; e0 < cntE; e0 += 8) {
    const int nb = cntE - e0;   // valid edges this chunk: min(nb, 8)
    int jj[8];
#pragma unroll
    for (int t = 0; t < 8; ++t)
      jj[t] = (t < nb) ? csr[beg + e0 + t] : node;
    ushort4 u[8];
#pragma unroll
    for (int t = 0; t < 8; ++t)
      u[t] = *(const ushort4*)&xl[(size_t)jj[t] * HC + v0];
    float lg[8];
#pragma unroll
    for (int t = 0; t < 8; ++t) {
      float part = 0.f;
#pragma unroll
      for (int m = 0; m < 4; ++m) {
        float xv = bf2f(((const u16*)&u[t])[m]);
        float s = xv + xrv[m];
        s = (s > 0.f) ? s : NEG * s;
        part = fmaf(attv[m], s, part);
      }
      part += __shfl_xor(part, 1);
      part += __shfl_xor(part, 2);
      part += __shfl_xor(part, 4);
      lg[t] = (t < nb) ? part : -INFINITY;
    }
    float mb = lg[0];
#pragma unroll
    for (int t = 1; t < 8; ++t) mb = fmaxf(mb, lg[t]);
    const float m_new = fmaxf(m_run, mb);
    const float r = __expf(m_run - m_new);
    d_run *= r;
#pragma unroll
    for (int m = 0; m < 4; ++m) agg[m] *= r;
#pragma unroll
    for (int t = 0; t < 8; ++t) {
      float p = __expf(lg[t] - m_new);     // 0 for padded slots
      d_run += p;
#pragma unroll
      for (int m = 0; m < 4; ++m)
        agg[m] = fmaf(p, bf2f(((const u16*)&u[t])[m]), agg[m]);
    }
    m_run = m_new;
  }
  const float inv = 1.f / d_run;
  float xv[4], bg[4];
  *(float4*)xv = *(const float4*)&x[(size_t)node * HC + v0];
  *(float4*)bg = *(const float4*)&b_gat[v0];
  float outv[4];
  float s1 = 0.f, s2 = 0.f;
#pragma unroll
  for (int m = 0; m < 4; ++m) {
    float v = fmaf(agg[m], inv, bg[m]) + xv[m];  // y = x + gat_out
    outv[m] = v;
    s1 += v;
    s2 += v * v;
  }
  *(float4*)&y[(size_t)node * HC + v0] = *(float4*)outv;
#pragma unroll
  for (int d = 1; d < 64; d <<= 1) {
    s1 += __shfl_xor(s1, d);
    s2 += __shfl_xor(s2, d);
  }
  if (lane == 0) {
    atomicAdd(&stats[0], (double)s1);
    atomicAdd(&stats[1], (double)s2);
  }
}

// ---------------- LayerNorm finalize: fold (mu, std) into per-column affine ----------------
__global__ void ln_final(const double* __restrict__ S, const float* __restrict__ g,
                         const float* __restrict__ be, float* __restrict__ Aout,
                         float* __restrict__ Bout, double cnt) {
  double mu = S[0] / cnt;
  double var = S[1] / cnt - mu * mu;
  if (var < 0.0) var = 0.0;
  float sc = (float)(1.0 / (sqrt(var) + (double)LN_EPS));
  int c = threadIdx.x;
  float gg = g[c];
  Aout[c] = sc * gg;
  Bout[c] = be[c] - (float)mu * sc * gg;
}

// ---------------- apply LN3 in place on d_out ----------------
__global__ void ln_apply(float* __restrict__ z, const float* __restrict__ A3,
                         const float* __restrict__ B3, long total4) {
  for (long i = blockIdx.x * (long)blockDim.x + threadIdx.x; i < total4;
       i += (long)gridDim.x * blockDim.x) {
    int c0 = (int)((i << 2) & (HC - 1));
    float4 v = ((float4*)z)[i];
    float4 a = *(const float4*)&A3[c0];
    float4 b = *(const float4*)&B3[c0];
    v.x = fmaf(v.x, a.x, b.x);
    v.y = fmaf(v.y, a.y, b.y);
    v.z = fmaf(v.z, a.z, b.z);
    v.w = fmaf(v.w, a.w, b.w);
    ((float4*)z)[i] = v;
  }
}

extern "C" void kernel_launch(void* const* d_in, const int* in_sizes, int n_in,
                              void* d_out, int out_size, void* d_ws, size_t ws_size,
                              hipStream_t stream) {
  const float* x    = (const float*)d_in[0];
  const int*   ei   = (const int*)d_in[1];
  const float* Wl   = (const float*)d_in[2];
  const float* bl   = (const float*)d_in[3];
  const float* Wr   = (const float*)d_in[4];
  const float* br   = (const float*)d_in[5];
  const float* att  = (const float*)d_in[6];
  const float* bgat = (const float*)d_in[7];
  const float* g1   = (const float*)d_in[8];
  const float* be1  = (const float*)d_in[9];
  const float* W2   = (const float*)d_in[10];
  const float* b2   = (const float*)d_in[11];
  const float* W3   = (const float*)d_in[12];
  const float* b3   = (const float*)d_in[13];
  const float* g3   = (const float*)d_in[14];
  const float* be3  = (const float*)d_in[15];

  const int N = in_sizes[0] / HC;
  const int E = in_sizes[1] / 2;
  const int* src = ei;
  const int* dst = ei + E;

  char* ws = (char*)d_ws;
  size_t o = 0;
  double* stats = (double*)(ws + o); o += 64;              // 4 doubles (LN1: 0,1  LN3: 2,3)
  float* A1 = (float*)(ws + o); o += HC * 4;
  float* B1 = (float*)(ws + o); o += HC * 4;
  float* A3 = (float*)(ws + o); o += HC * 4;
  float* B3 = (float*)(ws + o); o += HC * 4;
  int* deg = (int*)(ws + o); o += (size_t)N * 4;
  int* cur = (int*)(ws + o); o += (size_t)N * 4;           // contiguous with deg (one memset)
  int* off = (int*)(ws + o); o += (size_t)(N + 1) * 4; o = (o + 15) & ~(size_t)15;
  int* csr = (int*)(ws + o); o += (size_t)E * 4; o = (o + 15) & ~(size_t)15;
  u16* xl = (u16*)(ws + o); o += (size_t)N * HC * 2;
  u16* xr = (u16*)(ws + o); o += (size_t)N * HC * 2;
  u16* h2 = (u16*)(ws + o); o += (size_t)N * DHID * 2;

  float* y = (float*)d_out;   // y (= x + gat_out) lives in d_out until GEMM2 consumes it
  float* z = (float*)d_out;   // then z (= h2@W3+b3) overwrites it; LN3 applied in place

  hipMemsetAsync(stats, 0, 64, stream);
  hipMemsetAsync(deg, 0, (size_t)N * 8, stream);           // deg + cur

  dim3 blk(256);
  const int mb = (N + 63) / 64;

  gemm_xw_bf16<<<dim3(mb, HC / 64), blk, 0, stream>>>(x, Wl, bl, xl, N, HC, HC);
  gemm_xw_bf16<<<dim3(mb, HC / 64), blk, 0, stream>>>(x, Wr, br, xr, N, HC, HC);

  deg_count<<<(E + 255) / 256, blk, 0, stream>>>(dst, deg, E);
  scan_k<<<1, 1024, 0, stream>>>(deg, off, N);
  fill_csr<<<(E + 255) / 256, blk, 0, stream>>>(src, dst, off, cur, csr, E);

  gat_agg<<<(N + 3) / 4, blk, 0, stream>>>(xl, xr, x, off, csr, att, bgat, y, stats, N);

  ln_final<<<1, HC, 0, stream>>>(stats, g1, be1, A1, B1, (double)N * HC);

  gemm_h1w2<<<dim3(mb, DHID / 64), blk, 0, stream>>>(y, A1, B1, W2, b2, h2, N, HC, DHID);

  gemm_h2w3<<<dim3(mb, HC / 64), blk, 0, stream>>>(h2, W3, b3, z, stats + 2, N, DHID, HC);

  ln_final<<<1, HC, 0, stream>>>(stats + 2, g3, be3, A3, B3, (double)N * HC);

  ln_apply<<<2048, blk, 0, stream>>>(z, A3, B3, (long)N * HC / 4);
}

// Round 3
// 1133.089 us; speedup vs baseline: 2.0997x; 2.0997x over previous
//
#include <hip/hip_runtime.h>
#include <hip/hip_bf16.h>

#define HC 256      // H*C == IN
#define DHID 1024
#define NEG 0.2f
#define LN_EPS 1e-5f
#define NSLOT 1024  // distributed LN-stat accumulator slots (pairs of doubles)

typedef unsigned short u16;
typedef unsigned int u32;

__device__ __forceinline__ float bf2f(u16 u) {
  union { u32 i; float f; } v; v.i = ((u32)u) << 16; return v.f;
}
__device__ __forceinline__ u16 f2bf(float f) {
  union { float f; u32 i; } v; v.f = f;
  u32 r = v.i + 0x7fffu + ((v.i >> 16) & 1u);
  return (u16)(r >> 16);
}

// ---------------- GEMM 1: out_bf16 = A(f32)[M,K] @ B(f32)[K,NB] + bias ----------------
__global__ __launch_bounds__(256) void gemm_xw_bf16(
    const float* __restrict__ A, const float* __restrict__ B,
    const float* __restrict__ bias, u16* __restrict__ out,
    int M, int K, int NB)
{
  __shared__ float As[16][64];
  __shared__ float Bs[16][64];
  const int tid = threadIdx.x;
  const int tx = tid & 15, ty = tid >> 4;
  const int rowBase = blockIdx.x * 64;
  const int colBase = blockIdx.y * 64;
  const int la_r = tid >> 2, la_k = (tid & 3) << 2;
  const int lb_k = tid >> 4, lb_c = (tid & 15) << 2;
  float acc[4][4] = {};
  for (int k0 = 0; k0 < K; k0 += 16) {
    int ar = rowBase + la_r;
    float4 av = make_float4(0.f, 0.f, 0.f, 0.f);
    if (ar < M) av = *(const float4*)&A[(size_t)ar * K + k0 + la_k];
    As[la_k + 0][la_r] = av.x; As[la_k + 1][la_r] = av.y;
    As[la_k + 2][la_r] = av.z; As[la_k + 3][la_r] = av.w;
    *(float4*)&Bs[lb_k][lb_c] = *(const float4*)&B[(size_t)(k0 + lb_k) * NB + colBase + lb_c];
    __syncthreads();
#pragma unroll
    for (int k = 0; k < 16; ++k) {
      float a_[4], b_[4];
      *(float4*)a_ = *(const float4*)&As[k][ty << 2];
      *(float4*)b_ = *(const float4*)&Bs[k][tx << 2];
#pragma unroll
      for (int i = 0; i < 4; ++i)
#pragma unroll
        for (int j = 0; j < 4; ++j)
          acc[i][j] = fmaf(a_[i], b_[j], acc[i][j]);
    }
    __syncthreads();
  }
#pragma unroll
  for (int i = 0; i < 4; ++i) {
    int r = rowBase + (ty << 2) + i;
    if (r >= M) continue;
#pragma unroll
    for (int j = 0; j < 4; ++j) {
      int c = colBase + (tx << 2) + j;
      out[(size_t)r * NB + c] = f2bf(acc[i][j] + bias[c]);
    }
  }
}

// ---------------- GEMM 2: h2 = relu( (y*A1+B1) @ W2 + b2 ), bf16 out ----------------
__global__ __launch_bounds__(256) void gemm_h1w2(
    const float* __restrict__ Y, const float* __restrict__ A1c, const float* __restrict__ B1c,
    const float* __restrict__ B, const float* __restrict__ bias,
    u16* __restrict__ out, int M, int K, int NB)
{
  __shared__ float As[16][64];
  __shared__ float Bs[16][64];
  const int tid = threadIdx.x;
  const int tx = tid & 15, ty = tid >> 4;
  const int rowBase = blockIdx.x * 64;
  const int colBase = blockIdx.y * 64;
  const int la_r = tid >> 2, la_k = (tid & 3) << 2;
  const int lb_k = tid >> 4, lb_c = (tid & 15) << 2;
  float acc[4][4] = {};
  for (int k0 = 0; k0 < K; k0 += 16) {
    int ar = rowBase + la_r;
    float4 av = make_float4(0.f, 0.f, 0.f, 0.f);
    if (ar < M) {
      float4 yv = *(const float4*)&Y[(size_t)ar * K + k0 + la_k];
      float4 aa = *(const float4*)&A1c[k0 + la_k];
      float4 bb = *(const float4*)&B1c[k0 + la_k];
      av.x = fmaf(yv.x, aa.x, bb.x);
      av.y = fmaf(yv.y, aa.y, bb.y);
      av.z = fmaf(yv.z, aa.z, bb.z);
      av.w = fmaf(yv.w, aa.w, bb.w);
    }
    As[la_k + 0][la_r] = av.x; As[la_k + 1][la_r] = av.y;
    As[la_k + 2][la_r] = av.z; As[la_k + 3][la_r] = av.w;
    *(float4*)&Bs[lb_k][lb_c] = *(const float4*)&B[(size_t)(k0 + lb_k) * NB + colBase + lb_c];
    __syncthreads();
#pragma unroll
    for (int k = 0; k < 16; ++k) {
      float a_[4], b_[4];
      *(float4*)a_ = *(const float4*)&As[k][ty << 2];
      *(float4*)b_ = *(const float4*)&Bs[k][tx << 2];
#pragma unroll
      for (int i = 0; i < 4; ++i)
#pragma unroll
        for (int j = 0; j < 4; ++j)
          acc[i][j] = fmaf(a_[i], b_[j], acc[i][j]);
    }
    __syncthreads();
  }
#pragma unroll
  for (int i = 0; i < 4; ++i) {
    int r = rowBase + (ty << 2) + i;
    if (r >= M) continue;
#pragma unroll
    for (int j = 0; j < 4; ++j) {
      int c = colBase + (tx << 2) + j;
      float v = acc[i][j] + bias[c];
      v = fmaxf(v, 0.f);
      out[(size_t)r * NB + c] = f2bf(v);
    }
  }
}

// ---------------- GEMM 3: z(f32) = h2(bf16)[M,K] @ W3 + b3, + LN stats ----------------
__global__ __launch_bounds__(256) void gemm_h2w3(
    const u16* __restrict__ A, const float* __restrict__ B,
    const float* __restrict__ bias, float* __restrict__ out,
    double* __restrict__ sl, int M, int K, int NB)
{
  __shared__ float As[16][64];
  __shared__ float Bs[16][64];
  const int tid = threadIdx.x;
  const int tx = tid & 15, ty = tid >> 4;
  const int rowBase = blockIdx.x * 64;
  const int colBase = blockIdx.y * 64;
  const int la_r = tid >> 2, la_k = (tid & 3) << 2;
  const int lb_k = tid >> 4, lb_c = (tid & 15) << 2;
  float acc[4][4] = {};
  for (int k0 = 0; k0 < K; k0 += 16) {
    int ar = rowBase + la_r;
    float a0 = 0.f, a1 = 0.f, a2 = 0.f, a3 = 0.f;
    if (ar < M) {
      ushort4 u = *(const ushort4*)&A[(size_t)ar * K + k0 + la_k];
      a0 = bf2f(u.x); a1 = bf2f(u.y); a2 = bf2f(u.z); a3 = bf2f(u.w);
    }
    As[la_k + 0][la_r] = a0; As[la_k + 1][la_r] = a1;
    As[la_k + 2][la_r] = a2; As[la_k + 3][la_r] = a3;
    *(float4*)&Bs[lb_k][lb_c] = *(const float4*)&B[(size_t)(k0 + lb_k) * NB + colBase + lb_c];
    __syncthreads();
#pragma unroll
    for (int k = 0; k < 16; ++k) {
      float a_[4], b_[4];
      *(float4*)a_ = *(const float4*)&As[k][ty << 2];
      *(float4*)b_ = *(const float4*)&Bs[k][tx << 2];
#pragma unroll
      for (int i = 0; i < 4; ++i)
#pragma unroll
        for (int j = 0; j < 4; ++j)
          acc[i][j] = fmaf(a_[i], b_[j], acc[i][j]);
    }
    __syncthreads();
  }
  float s1 = 0.f, s2 = 0.f;
#pragma unroll
  for (int i = 0; i < 4; ++i) {
    int r = rowBase + (ty << 2) + i;
    if (r >= M) continue;
#pragma unroll
    for (int j = 0; j < 4; ++j) {
      int c = colBase + (tx << 2) + j;
      float v = acc[i][j] + bias[c];
      out[(size_t)r * NB + c] = v;
      s1 += v;
      s2 += v * v;
    }
  }
  // wave-level reduction of LN stats -> distributed slot (avoid same-address serialization)
#pragma unroll
  for (int d = 1; d < 64; d <<= 1) {
    s1 += __shfl_xor(s1, d);
    s2 += __shfl_xor(s2, d);
  }
  if ((threadIdx.x & 63) == 0) {
    int slot = ((blockIdx.x + blockIdx.y * 811) * 4 + (threadIdx.x >> 6)) & (NSLOT - 1);
    atomicAdd(&sl[slot * 2 + 0], (double)s1);
    atomicAdd(&sl[slot * 2 + 1], (double)s2);
  }
}

// ---------------- CSR build ----------------
__global__ void deg_count(const int* __restrict__ dst, int* __restrict__ deg, int E) {
  int i = blockIdx.x * blockDim.x + threadIdx.x;
  if (i < E) atomicAdd(&deg[dst[i]], 1);
}

__global__ __launch_bounds__(1024) void scan_k(const int* __restrict__ deg, int* __restrict__ off, int n) {
  __shared__ int wsum[16];
  __shared__ int carrySh;
  const int tid = threadIdx.x, lane = tid & 63, w = tid >> 6;
  if (tid == 0) carrySh = 0;
  __syncthreads();
  for (int base = 0; base < n; base += 1024) {
    int i = base + tid;
    int v = (i < n) ? deg[i] : 0;
    int incl = v;
#pragma unroll
    for (int d = 1; d < 64; d <<= 1) {
      int t = __shfl_up(incl, d);
      if (lane >= d) incl += t;
    }
    if (lane == 63) wsum[w] = incl;
    __syncthreads();
    int waveOff = 0, total = 0;
#pragma unroll
    for (int k = 0; k < 16; ++k) {
      int s = wsum[k];
      if (k < w) waveOff += s;
      total += s;
    }
    int carry = carrySh;
    if (i < n) off[i] = carry + waveOff + incl - v;
    __syncthreads();
    if (tid == 0) carrySh = carry + total;
    __syncthreads();
  }
  if (threadIdx.x == 0) off[n] = carrySh;
}

__global__ void fill_csr(const int* __restrict__ src, const int* __restrict__ dst,
                         const int* __restrict__ off, int* __restrict__ cur,
                         int* __restrict__ csr, int E) {
  int i = blockIdx.x * blockDim.x + threadIdx.x;
  if (i < E) {
    int d = dst[i];
    int pos = off[d] + atomicAdd(&cur[d], 1);
    csr[pos] = src[i];
  }
}

// ---------------- fused GATv2 edge-softmax-aggregate: one wave per node ----------------
__global__ __launch_bounds__(256) void gat_agg(
    const u16* __restrict__ xl, const u16* __restrict__ xr,
    const float* __restrict__ x, const int* __restrict__ off,
    const int* __restrict__ csr, const float* __restrict__ att,
    const float* __restrict__ b_gat, float* __restrict__ y,
    double* __restrict__ sl, int N)
{
  const int lane = threadIdx.x & 63;
  const int node = blockIdx.x * 4 + (threadIdx.x >> 6);
  if (node >= N) return;
  const int v0 = lane << 2;   // this lane's 4 feature slots; head = lane>>3
  float attv[4];
  *(float4*)attv = *(const float4*)&att[v0];
  float xrv[4];
  {
    ushort4 u = *(const ushort4*)&xr[(size_t)node * HC + v0];
    xrv[0] = bf2f(u.x); xrv[1] = bf2f(u.y); xrv[2] = bf2f(u.z); xrv[3] = bf2f(u.w);
  }
  // self-loop initializes the online softmax state
  float m_run, d_run = 1.f;
  float agg[4];
  {
    ushort4 u = *(const ushort4*)&xl[(size_t)node * HC + v0];
    float xlv[4] = {bf2f(u.x), bf2f(u.y), bf2f(u.z), bf2f(u.w)};
    float part = 0.f;
#pragma unroll
    for (int m = 0; m < 4; ++m) {
      float s = xlv[m] + xrv[m];
      s = (s > 0.f) ? s : NEG * s;
      part = fmaf(attv[m], s, part);
    }
    part += __shfl_xor(part, 1);
    part += __shfl_xor(part, 2);
    part += __shfl_xor(part, 4);
    m_run = part;
#pragma unroll
    for (int m = 0; m < 4; ++m) agg[m] = xlv[m];
  }
  const int beg = off[node];
  const int cntE = off[node + 1] - beg;
  for (int e0 = 0; e0 < cntE; e0 += 8) {
    const int nb = cntE - e0;   // valid edges this chunk: min(nb, 8)
    int jj[8];
#pragma unroll
    for (int t = 0; t < 8; ++t)
      jj[t] = (t < nb) ? csr[beg + e0 + t] : node;
    ushort4 u[8];
#pragma unroll
    for (int t = 0; t < 8; ++t)
      u[t] = *(const ushort4*)&xl[(size_t)jj[t] * HC + v0];
    float lg[8];
#pragma unroll
    for (int t = 0; t < 8; ++t) {
      float part = 0.f;
#pragma unroll
      for (int m = 0; m < 4; ++m) {
        float xv = bf2f(((const u16*)&u[t])[m]);
        float s = xv + xrv[m];
        s = (s > 0.f) ? s : NEG * s;
        part = fmaf(attv[m], s, part);
      }
      part += __shfl_xor(part, 1);
      part += __shfl_xor(part, 2);
      part += __shfl_xor(part, 4);
      lg[t] = (t < nb) ? part : -INFINITY;
    }
    float mb = lg[0];
#pragma unroll
    for (int t = 1; t < 8; ++t) mb = fmaxf(mb, lg[t]);
    const float m_new = fmaxf(m_run, mb);
    const float r = __expf(m_run - m_new);
    d_run *= r;
#pragma unroll
    for (int m = 0; m < 4; ++m) agg[m] *= r;
#pragma unroll
    for (int t = 0; t < 8; ++t) {
      float p = __expf(lg[t] - m_new);     // 0 for padded slots
      d_run += p;
#pragma unroll
      for (int m = 0; m < 4; ++m)
        agg[m] = fmaf(p, bf2f(((const u16*)&u[t])[m]), agg[m]);
    }
    m_run = m_new;
  }
  const float inv = 1.f / d_run;
  float xv[4], bg[4];
  *(float4*)xv = *(const float4*)&x[(size_t)node * HC + v0];
  *(float4*)bg = *(const float4*)&b_gat[v0];
  float outv[4];
  float s1 = 0.f, s2 = 0.f;
#pragma unroll
  for (int m = 0; m < 4; ++m) {
    float v = fmaf(agg[m], inv, bg[m]) + xv[m];  // y = x + gat_out
    outv[m] = v;
    s1 += v;
    s2 += v * v;
  }
  *(float4*)&y[(size_t)node * HC + v0] = *(float4*)outv;
#pragma unroll
  for (int d = 1; d < 64; d <<= 1) {
    s1 += __shfl_xor(s1, d);
    s2 += __shfl_xor(s2, d);
  }
  if (lane == 0) {
    int slot = node & (NSLOT - 1);
    atomicAdd(&sl[slot * 2 + 0], (double)s1);
    atomicAdd(&sl[slot * 2 + 1], (double)s2);
  }
}

// ---------------- LayerNorm finalize: reduce slots, fold (mu, std) into affine ----------------
__global__ __launch_bounds__(256) void ln_final(const double* __restrict__ sl,
                                                const float* __restrict__ g,
                                                const float* __restrict__ be,
                                                float* __restrict__ Aout,
                                                float* __restrict__ Bout, double cnt) {
  __shared__ double red[256][2];
  const int tid = threadIdx.x;
  double s1 = 0.0, s2 = 0.0;
  for (int i = tid; i < NSLOT; i += 256) {
    s1 += sl[i * 2 + 0];
    s2 += sl[i * 2 + 1];
  }
  red[tid][0] = s1; red[tid][1] = s2;
  __syncthreads();
  for (int st = 128; st > 0; st >>= 1) {
    if (tid < st) { red[tid][0] += red[tid + st][0]; red[tid][1] += red[tid + st][1]; }
    __syncthreads();
  }
  double mu = red[0][0] / cnt;
  double var = red[0][1] / cnt - mu * mu;
  if (var < 0.0) var = 0.0;
  float sc = (float)(1.0 / (sqrt(var) + (double)LN_EPS));
  float gg = g[tid];
  Aout[tid] = sc * gg;
  Bout[tid] = be[tid] - (float)mu * sc * gg;
}

// ---------------- apply LN3 in place on d_out ----------------
__global__ void ln_apply(float* __restrict__ z, const float* __restrict__ A3,
                         const float* __restrict__ B3, long total4) {
  for (long i = blockIdx.x * (long)blockDim.x + threadIdx.x; i < total4;
       i += (long)gridDim.x * blockDim.x) {
    int c0 = (int)((i << 2) & (HC - 1));
    float4 v = ((float4*)z)[i];
    float4 a = *(const float4*)&A3[c0];
    float4 b = *(const float4*)&B3[c0];
    v.x = fmaf(v.x, a.x, b.x);
    v.y = fmaf(v.y, a.y, b.y);
    v.z = fmaf(v.z, a.z, b.z);
    v.w = fmaf(v.w, a.w, b.w);
    ((float4*)z)[i] = v;
  }
}

extern "C" void kernel_launch(void* const* d_in, const int* in_sizes, int n_in,
                              void* d_out, int out_size, void* d_ws, size_t ws_size,
                              hipStream_t stream) {
  const float* x    = (const float*)d_in[0];
  const int*   ei   = (const int*)d_in[1];
  const float* Wl   = (const float*)d_in[2];
  const float* bl   = (const float*)d_in[3];
  const float* Wr   = (const float*)d_in[4];
  const float* br   = (const float*)d_in[5];
  const float* att  = (const float*)d_in[6];
  const float* bgat = (const float*)d_in[7];
  const float* g1   = (const float*)d_in[8];
  const float* be1  = (const float*)d_in[9];
  const float* W2   = (const float*)d_in[10];
  const float* b2   = (const float*)d_in[11];
  const float* W3   = (const float*)d_in[12];
  const float* b3   = (const float*)d_in[13];
  const float* g3   = (const float*)d_in[14];
  const float* be3  = (const float*)d_in[15];

  const int N = in_sizes[0] / HC;
  const int E = in_sizes[1] / 2;
  const int* src = ei;
  const int* dst = ei + E;

  char* ws = (char*)d_ws;
  size_t o = 0;
  double* sl1 = (double*)(ws + o); o += (size_t)NSLOT * 16;   // LN1 slot pairs
  double* sl3 = (double*)(ws + o); o += (size_t)NSLOT * 16;   // LN3 slot pairs
  float* A1 = (float*)(ws + o); o += HC * 4;
  float* B1 = (float*)(ws + o); o += HC * 4;
  float* A3 = (float*)(ws + o); o += HC * 4;
  float* B3 = (float*)(ws + o); o += HC * 4;
  int* deg = (int*)(ws + o); o += (size_t)N * 4;
  int* cur = (int*)(ws + o); o += (size_t)N * 4;           // contiguous with deg (one memset)
  int* off = (int*)(ws + o); o += (size_t)(N + 1) * 4; o = (o + 15) & ~(size_t)15;
  int* csr = (int*)(ws + o); o += (size_t)E * 4; o = (o + 15) & ~(size_t)15;
  u16* xl = (u16*)(ws + o); o += (size_t)N * HC * 2;
  u16* xr = (u16*)(ws + o); o += (size_t)N * HC * 2;
  u16* h2 = (u16*)(ws + o); o += (size_t)N * DHID * 2;

  float* y = (float*)d_out;   // y (= x + gat_out) lives in d_out until GEMM2 consumes it
  float* z = (float*)d_out;   // then z (= h2@W3+b3) overwrites it; LN3 applied in place

  hipMemsetAsync(sl1, 0, (size_t)NSLOT * 32, stream);      // sl1 + sl3
  hipMemsetAsync(deg, 0, (size_t)N * 8, stream);           // deg + cur

  dim3 blk(256);
  const int mb = (N + 63) / 64;

  gemm_xw_bf16<<<dim3(mb, HC / 64), blk, 0, stream>>>(x, Wl, bl, xl, N, HC, HC);
  gemm_xw_bf16<<<dim3(mb, HC / 64), blk, 0, stream>>>(x, Wr, br, xr, N, HC, HC);

  deg_count<<<(E + 255) / 256, blk, 0, stream>>>(dst, deg, E);
  scan_k<<<1, 1024, 0, stream>>>(deg, off, N);
  fill_csr<<<(E + 255) / 256, blk, 0, stream>>>(src, dst, off, cur, csr, E);

  gat_agg<<<(N + 3) / 4, blk, 0, stream>>>(xl, xr, x, off, csr, att, bgat, y, sl1, N);

  ln_final<<<1, 256, 0, stream>>>(sl1, g1, be1, A1, B1, (double)N * HC);

  gemm_h1w2<<<dim3(mb, DHID / 64), blk, 0, stream>>>(y, A1, B1, W2, b2, h2, N, HC, DHID);

  gemm_h2w3<<<dim3(mb, HC / 64), blk, 0, stream>>>(h2, W3, b3, z, sl3, N, DHID, HC);

  ln_final<<<1, 256, 0, stream>>>(sl3, g3, be3, A3, B3, (double)N * HC);

  ln_apply<<<2048, blk, 0, stream>>>(z, A3, B3, (long)N * HC / 4);
}

// Round 4
// 550.466 us; speedup vs baseline: 4.3220x; 2.0584x over previous
//
#include <hip/hip_runtime.h>
#include <hip/hip_bf16.h>

#define HC 256      // H*C == IN
#define DHID 1024
#define NEG 0.2f
#define LN_EPS 1e-5f
#define NSLOT 1024  // distributed LN-stat accumulator slots (pairs of doubles)

typedef unsigned short u16;
typedef unsigned int u32;
typedef __attribute__((ext_vector_type(8))) short bf16x8;   // 8 bf16 = 4 VGPRs
typedef __attribute__((ext_vector_type(4))) float f32x4;

__device__ __forceinline__ float bf2f(u16 u) {
  union { u32 i; float f; } v; v.i = ((u32)u) << 16; return v.f;
}
__device__ __forceinline__ u16 f2bf(float f) {
  union { float f; u32 i; } v; v.f = f;
  u32 r = v.i + 0x7fffu + ((v.i >> 16) & 1u);
  return (u16)(r >> 16);
}

// ================= MFMA GEMM: out = op(A @ B^T_rowmajor + bias) =================
// A: [M x K] (f32 if A_F32 else bf16), BT: [NB x K] bf16 (pre-transposed B),
// 128x128 tile, BK=64, 4 waves x (64x64 via 4x4 16x16x32 fragments).
// Fragment layouts (gfx950, m89-verified C/D): A lane l holds A[l&15][g*8+j],
// B lane l holds B[g*8+j][l&15] (g=l>>4); D: col=lane&15, row=(lane>>4)*4+reg.
template<bool A_F32, bool RELU, bool OUT_BF16, bool LN>
__global__ __launch_bounds__(256) void gemm_mfma(
    const float* __restrict__ Af, const u16* __restrict__ Ab,
    const u16* __restrict__ BT, const float* __restrict__ bias,
    void* __restrict__ outp, double* __restrict__ sl,
    int M, int K, int NB)
{
  __shared__ __align__(16) u16 As[128][72];   // pitch 72 (144B): pad kills 32-bank stride
  __shared__ __align__(16) u16 Bs[128][72];
  const int tid = threadIdx.x;
  const int wid = tid >> 6, lane = tid & 63;
  const int rowBase = blockIdx.x * 128;
  const int colBase = blockIdx.y * 128;
  const int wr = (wid >> 1) * 64, wc = (wid & 1) * 64;
  f32x4 acc[4][4] = {};

  for (int k0 = 0; k0 < K; k0 += 64) {
    // ---- stage A tile 128x64 (4 x bf16x8 per thread) ----
#pragma unroll
    for (int s = 0; s < 4; ++s) {
      const int L = tid + s * 256;
      const int r = L >> 3, cb = (L & 7) << 3;
      const int gr = rowBase + r;
      bf16x8 v = {};
      if (A_F32) {
        if (gr < M) {
          const float* p = &Af[(size_t)gr * K + k0 + cb];
          float4 f0 = *(const float4*)p;
          float4 f1 = *(const float4*)(p + 4);
          v[0] = (short)f2bf(f0.x); v[1] = (short)f2bf(f0.y);
          v[2] = (short)f2bf(f0.z); v[3] = (short)f2bf(f0.w);
          v[4] = (short)f2bf(f1.x); v[5] = (short)f2bf(f1.y);
          v[6] = (short)f2bf(f1.z); v[7] = (short)f2bf(f1.w);
        }
      } else {
        if (gr < M) v = *(const bf16x8*)&Ab[(size_t)gr * K + k0 + cb];
      }
      *(bf16x8*)&As[r][cb] = v;
    }
    // ---- stage B^T tile 128x64 (NB multiple of 128 -> no guard) ----
#pragma unroll
    for (int s = 0; s < 4; ++s) {
      const int L = tid + s * 256;
      const int r = L >> 3, cb = (L & 7) << 3;
      *(bf16x8*)&Bs[r][cb] = *(const bf16x8*)&BT[(size_t)(colBase + r) * K + k0 + cb];
    }
    __syncthreads();
    // ---- 32 MFMAs per wave ----
#pragma unroll
    for (int kk = 0; kk < 2; ++kk) {
      bf16x8 af[4], bfr[4];
#pragma unroll
      for (int mr = 0; mr < 4; ++mr)
        af[mr] = *(const bf16x8*)&As[wr + mr * 16 + (lane & 15)][kk * 32 + (lane >> 4) * 8];
#pragma unroll
      for (int nc = 0; nc < 4; ++nc)
        bfr[nc] = *(const bf16x8*)&Bs[wc + nc * 16 + (lane & 15)][kk * 32 + (lane >> 4) * 8];
#pragma unroll
      for (int mr = 0; mr < 4; ++mr)
#pragma unroll
        for (int nc = 0; nc < 4; ++nc)
          acc[mr][nc] = __builtin_amdgcn_mfma_f32_16x16x32_bf16(af[mr], bfr[nc], acc[mr][nc], 0, 0, 0);
    }
    __syncthreads();
  }

  // ---- epilogue ----
  u16* ob = (u16*)outp;
  float* of = (float*)outp;
  const int crow = (lane >> 4) * 4;
  const int ccol = lane & 15;
  float s1 = 0.f, s2 = 0.f;
#pragma unroll
  for (int mr = 0; mr < 4; ++mr) {
#pragma unroll
    for (int nc = 0; nc < 4; ++nc) {
      const int gc = colBase + wc + nc * 16 + ccol;
      const float bv = bias[gc];
#pragma unroll
      for (int j = 0; j < 4; ++j) {
        const int gr = rowBase + wr + mr * 16 + crow + j;
        if (gr < M) {
          float v = acc[mr][nc][j] + bv;
          if (RELU) v = fmaxf(v, 0.f);
          if (OUT_BF16) {
            ob[(size_t)gr * NB + gc] = f2bf(v);
          } else {
            of[(size_t)gr * NB + gc] = v;
            s1 += v; s2 += v * v;
          }
        }
      }
    }
  }
  if (LN) {
#pragma unroll
    for (int d = 1; d < 64; d <<= 1) {
      s1 += __shfl_xor(s1, d);
      s2 += __shfl_xor(s2, d);
    }
    if (lane == 0) {
      int slot = ((blockIdx.x + blockIdx.y * 397) * 4 + wid) & (NSLOT - 1);
      atomicAdd(&sl[slot * 2 + 0], (double)s1);
      atomicAdd(&sl[slot * 2 + 1], (double)s2);
    }
  }
}

// ============ transpose + (optional per-k scale) + f32->bf16: WT[n][k] = sc[k]*W[k][n] ============
__global__ __launch_bounds__(256) void transpose_bf16(
    const float* __restrict__ W, const float* __restrict__ scale,
    u16* __restrict__ WT, int K, int NB)
{
  __shared__ float T[32][33];
  const int k0 = blockIdx.x * 32, n0 = blockIdx.y * 32;
  const int tx = threadIdx.x & 31, ty = threadIdx.x >> 5;   // 32 x 8
#pragma unroll
  for (int i = 0; i < 32; i += 8) {
    float v = W[(size_t)(k0 + ty + i) * NB + n0 + tx];
    if (scale) v *= scale[k0 + ty + i];
    T[ty + i][tx] = v;
  }
  __syncthreads();
#pragma unroll
  for (int i = 0; i < 32; i += 8)
    WT[(size_t)(n0 + ty + i) * K + k0 + tx] = f2bf(T[tx][ty + i]);
}

// ============ bias2' = b2 + B1 . W2  (row-vector x matrix) ============
__global__ void bias_fold(const float* __restrict__ b2, const float* __restrict__ B1c,
                          const float* __restrict__ W2, float* __restrict__ out,
                          int K, int NB) {
  const int n = blockIdx.x * blockDim.x + threadIdx.x;
  if (n < NB) {
    float s = b2[n];
    for (int k = 0; k < K; ++k) s = fmaf(B1c[k], W2[(size_t)k * NB + n], s);
    out[n] = s;
  }
}

// ---------------- CSR build ----------------
__global__ void deg_count(const int* __restrict__ dst, int* __restrict__ deg, int E) {
  int i = blockIdx.x * blockDim.x + threadIdx.x;
  if (i < E) atomicAdd(&deg[dst[i]], 1);
}

__global__ __launch_bounds__(1024) void scan_k(const int* __restrict__ deg, int* __restrict__ off, int n) {
  __shared__ int wsum[16];
  __shared__ int carrySh;
  const int tid = threadIdx.x, lane = tid & 63, w = tid >> 6;
  if (tid == 0) carrySh = 0;
  __syncthreads();
  for (int base = 0; base < n; base += 1024) {
    int i = base + tid;
    int v = (i < n) ? deg[i] : 0;
    int incl = v;
#pragma unroll
    for (int d = 1; d < 64; d <<= 1) {
      int t = __shfl_up(incl, d);
      if (lane >= d) incl += t;
    }
    if (lane == 63) wsum[w] = incl;
    __syncthreads();
    int waveOff = 0, total = 0;
#pragma unroll
    for (int k = 0; k < 16; ++k) {
      int s = wsum[k];
      if (k < w) waveOff += s;
      total += s;
    }
    int carry = carrySh;
    if (i < n) off[i] = carry + waveOff + incl - v;
    __syncthreads();
    if (tid == 0) carrySh = carry + total;
    __syncthreads();
  }
  if (threadIdx.x == 0) off[n] = carrySh;
}

__global__ void fill_csr(const int* __restrict__ src, const int* __restrict__ dst,
                         const int* __restrict__ off, int* __restrict__ cur,
                         int* __restrict__ csr, int E) {
  int i = blockIdx.x * blockDim.x + threadIdx.x;
  if (i < E) {
    int d = dst[i];
    int pos = off[d] + atomicAdd(&cur[d], 1);
    csr[pos] = src[i];
  }
}

// ---------------- fused GATv2 edge-softmax-aggregate: one wave per node ----------------
// xlr: [N][512] bf16, cols 0..255 = xl (lin_l), 256..511 = xr (lin_r).
// Writes y = x + gat_out as bf16 into ybf; LN1 stats into distributed slots.
__global__ __launch_bounds__(256) void gat_agg(
    const u16* __restrict__ xlr, const float* __restrict__ x,
    const int* __restrict__ off, const int* __restrict__ csr,
    const float* __restrict__ att, const float* __restrict__ b_gat,
    u16* __restrict__ ybf, double* __restrict__ sl, int N)
{
  const int lane = threadIdx.x & 63;
  const int node = blockIdx.x * 4 + (threadIdx.x >> 6);
  if (node >= N) return;
  const int v0 = lane << 2;   // 4 feature slots per lane; head = lane>>3
  float attv[4];
  *(float4*)attv = *(const float4*)&att[v0];
  float xrv[4];
  {
    ushort4 u = *(const ushort4*)&xlr[(size_t)node * 512 + 256 + v0];
    xrv[0] = bf2f(u.x); xrv[1] = bf2f(u.y); xrv[2] = bf2f(u.z); xrv[3] = bf2f(u.w);
  }
  // self-loop initializes the online softmax state
  float m_run, d_run = 1.f;
  float agg[4];
  {
    ushort4 u = *(const ushort4*)&xlr[(size_t)node * 512 + v0];
    float xlv[4] = {bf2f(u.x), bf2f(u.y), bf2f(u.z), bf2f(u.w)};
    float part = 0.f;
#pragma unroll
    for (int m = 0; m < 4; ++m) {
      float s = xlv[m] + xrv[m];
      s = (s > 0.f) ? s : NEG * s;
      part = fmaf(attv[m], s, part);
    }
    part += __shfl_xor(part, 1);
    part += __shfl_xor(part, 2);
    part += __shfl_xor(part, 4);
    m_run = part;
#pragma unroll
    for (int m = 0; m < 4; ++m) agg[m] = xlv[m];
  }
  const int beg = off[node];
  const int cntE = off[node + 1] - beg;
  for (int e0 = 0; e0 < cntE; e0 += 8) {
    const int nb = cntE - e0;
    int jj[8];
#pragma unroll
    for (int t = 0; t < 8; ++t)
      jj[t] = (t < nb) ? csr[beg + e0 + t] : node;
    ushort4 u[8];
#pragma unroll
    for (int t = 0; t < 8; ++t)
      u[t] = *(const ushort4*)&xlr[(size_t)jj[t] * 512 + v0];
    float lg[8];
#pragma unroll
    for (int t = 0; t < 8; ++t) {
      float part = 0.f;
#pragma unroll
      for (int m = 0; m < 4; ++m) {
        float xv = bf2f(((const u16*)&u[t])[m]);
        float s = xv + xrv[m];
        s = (s > 0.f) ? s : NEG * s;
        part = fmaf(attv[m], s, part);
      }
      part += __shfl_xor(part, 1);
      part += __shfl_xor(part, 2);
      part += __shfl_xor(part, 4);
      lg[t] = (t < nb) ? part : -INFINITY;
    }
    float mb = lg[0];
#pragma unroll
    for (int t = 1; t < 8; ++t) mb = fmaxf(mb, lg[t]);
    const float m_new = fmaxf(m_run, mb);
    const float r = __expf(m_run - m_new);
    d_run *= r;
#pragma unroll
    for (int m = 0; m < 4; ++m) agg[m] *= r;
#pragma unroll
    for (int t = 0; t < 8; ++t) {
      float p = __expf(lg[t] - m_new);
      d_run += p;
#pragma unroll
      for (int m = 0; m < 4; ++m)
        agg[m] = fmaf(p, bf2f(((const u16*)&u[t])[m]), agg[m]);
    }
    m_run = m_new;
  }
  const float inv = 1.f / d_run;
  float xv[4], bg[4];
  *(float4*)xv = *(const float4*)&x[(size_t)node * HC + v0];
  *(float4*)bg = *(const float4*)&b_gat[v0];
  float s1 = 0.f, s2 = 0.f;
  ushort4 ov;
  {
    float v0f = fmaf(agg[0], inv, bg[0]) + xv[0];
    float v1f = fmaf(agg[1], inv, bg[1]) + xv[1];
    float v2f = fmaf(agg[2], inv, bg[2]) + xv[2];
    float v3f = fmaf(agg[3], inv, bg[3]) + xv[3];
    s1 = v0f + v1f + v2f + v3f;
    s2 = v0f * v0f + v1f * v1f + v2f * v2f + v3f * v3f;
    ov.x = f2bf(v0f); ov.y = f2bf(v1f); ov.z = f2bf(v2f); ov.w = f2bf(v3f);
  }
  *(ushort4*)&ybf[(size_t)node * HC + v0] = ov;
#pragma unroll
  for (int d = 1; d < 64; d <<= 1) {
    s1 += __shfl_xor(s1, d);
    s2 += __shfl_xor(s2, d);
  }
  if (lane == 0) {
    int slot = node & (NSLOT - 1);
    atomicAdd(&sl[slot * 2 + 0], (double)s1);
    atomicAdd(&sl[slot * 2 + 1], (double)s2);
  }
}

// ---------------- LayerNorm finalize: reduce slots, fold (mu, std) into affine ----------------
__global__ __launch_bounds__(256) void ln_final(const double* __restrict__ sl,
                                                const float* __restrict__ g,
                                                const float* __restrict__ be,
                                                float* __restrict__ Aout,
                                                float* __restrict__ Bout, double cnt) {
  __shared__ double red[256][2];
  const int tid = threadIdx.x;
  double s1 = 0.0, s2 = 0.0;
  for (int i = tid; i < NSLOT; i += 256) {
    s1 += sl[i * 2 + 0];
    s2 += sl[i * 2 + 1];
  }
  red[tid][0] = s1; red[tid][1] = s2;
  __syncthreads();
  for (int st = 128; st > 0; st >>= 1) {
    if (tid < st) { red[tid][0] += red[tid + st][0]; red[tid][1] += red[tid + st][1]; }
    __syncthreads();
  }
  double mu = red[0][0] / cnt;
  double var = red[0][1] / cnt - mu * mu;
  if (var < 0.0) var = 0.0;
  float sc = (float)(1.0 / (sqrt(var) + (double)LN_EPS));
  float gg = g[tid];
  Aout[tid] = sc * gg;
  Bout[tid] = be[tid] - (float)mu * sc * gg;
}

// ---------------- apply LN3 in place on d_out ----------------
__global__ void ln_apply(float* __restrict__ z, const float* __restrict__ A3,
                         const float* __restrict__ B3, long total4) {
  for (long i = blockIdx.x * (long)blockDim.x + threadIdx.x; i < total4;
       i += (long)gridDim.x * blockDim.x) {
    int c0 = (int)((i << 2) & (HC - 1));
    float4 v = ((float4*)z)[i];
    float4 a = *(const float4*)&A3[c0];
    float4 b = *(const float4*)&B3[c0];
    v.x = fmaf(v.x, a.x, b.x);
    v.y = fmaf(v.y, a.y, b.y);
    v.z = fmaf(v.z, a.z, b.z);
    v.w = fmaf(v.w, a.w, b.w);
    ((float4*)z)[i] = v;
  }
}

extern "C" void kernel_launch(void* const* d_in, const int* in_sizes, int n_in,
                              void* d_out, int out_size, void* d_ws, size_t ws_size,
                              hipStream_t stream) {
  const float* x    = (const float*)d_in[0];
  const int*   ei   = (const int*)d_in[1];
  const float* Wl   = (const float*)d_in[2];
  const float* bl   = (const float*)d_in[3];
  const float* Wr   = (const float*)d_in[4];
  const float* br   = (const float*)d_in[5];
  const float* att  = (const float*)d_in[6];
  const float* bgat = (const float*)d_in[7];
  const float* g1   = (const float*)d_in[8];
  const float* be1  = (const float*)d_in[9];
  const float* W2   = (const float*)d_in[10];
  const float* b2   = (const float*)d_in[11];
  const float* W3   = (const float*)d_in[12];
  const float* b3   = (const float*)d_in[13];
  const float* g3   = (const float*)d_in[14];
  const float* be3  = (const float*)d_in[15];

  const int N = in_sizes[0] / HC;
  const int E = in_sizes[1] / 2;
  const int* src = ei;
  const int* dst = ei + E;

  char* ws = (char*)d_ws;
  size_t o = 0;
  double* sl1 = (double*)(ws + o); o += (size_t)NSLOT * 16;
  double* sl3 = (double*)(ws + o); o += (size_t)NSLOT * 16;
  float* A1 = (float*)(ws + o); o += HC * 4;
  float* B1 = (float*)(ws + o); o += HC * 4;
  float* A3 = (float*)(ws + o); o += HC * 4;
  float* B3 = (float*)(ws + o); o += HC * 4;
  float* biascat = (float*)(ws + o); o += 512 * 4;
  float* bias2p = (float*)(ws + o); o += DHID * 4;
  u16* WT1 = (u16*)(ws + o); o += (size_t)512 * HC * 2;        // [WlT;WrT]: [512][256]
  u16* W2T = (u16*)(ws + o); o += (size_t)DHID * HC * 2;       // [1024][256], A1-scaled
  u16* W3T = (u16*)(ws + o); o += (size_t)HC * DHID * 2;       // [256][1024]
  int* deg = (int*)(ws + o); o += (size_t)N * 4;
  int* cur = (int*)(ws + o); o += (size_t)N * 4;               // contiguous with deg
  int* off = (int*)(ws + o); o += (size_t)(N + 1) * 4; o = (o + 15) & ~(size_t)15;
  int* csr = (int*)(ws + o); o += (size_t)E * 4; o = (o + 15) & ~(size_t)15;
  u16* xlr = (u16*)(ws + o); o += (size_t)N * 512 * 2;         // [N][512] = xl | xr
  u16* h2  = (u16*)(ws + o); o += (size_t)N * DHID * 2;

  u16* ybf = (u16*)d_out;    // y bf16 borrows d_out (first 25.6MB); GEMM3's z overwrites later
  float* z = (float*)d_out;

  hipMemsetAsync(sl1, 0, (size_t)NSLOT * 32, stream);          // sl1 + sl3
  hipMemsetAsync(deg, 0, (size_t)N * 8, stream);               // deg + cur
  hipMemcpyAsync(biascat, bl, 256 * 4, hipMemcpyDeviceToDevice, stream);
  hipMemcpyAsync(biascat + 256, br, 256 * 4, hipMemcpyDeviceToDevice, stream);

  dim3 blk(256);
  const int mb = (N + 127) / 128;

  // weight transposes (f32 -> bf16, B^T layout)
  transpose_bf16<<<dim3(8, 8), blk, 0, stream>>>(Wl, nullptr, WT1, HC, HC);
  transpose_bf16<<<dim3(8, 8), blk, 0, stream>>>(Wr, nullptr, WT1 + (size_t)256 * HC, HC, HC);
  transpose_bf16<<<dim3(32, 8), blk, 0, stream>>>(W3, nullptr, W3T, DHID, HC);

  // CSR build
  deg_count<<<(E + 255) / 256, blk, 0, stream>>>(dst, deg, E);
  scan_k<<<1, 1024, 0, stream>>>(deg, off, N);
  fill_csr<<<(E + 255) / 256, blk, 0, stream>>>(src, dst, off, cur, csr, E);

  // GEMM1: xlr = x @ [Wl|Wr] + [bl|br]   (A=f32 x, out bf16 [N][512])
  gemm_mfma<true, false, true, false><<<dim3(mb, 4), blk, 0, stream>>>(
      x, nullptr, WT1, biascat, xlr, nullptr, N, HC, 512);

  // fused GATv2 + residual + LN1 partial stats
  gat_agg<<<(N + 3) / 4, blk, 0, stream>>>(xlr, x, off, csr, att, bgat, ybf, sl1, N);

  ln_final<<<1, 256, 0, stream>>>(sl1, g1, be1, A1, B1, (double)N * HC);

  // fold LN1 affine into W2 / bias2
  transpose_bf16<<<dim3(8, 32), blk, 0, stream>>>(W2, A1, W2T, HC, DHID);
  bias_fold<<<4, 256, 0, stream>>>(b2, B1, W2, bias2p, HC, DHID);

  // GEMM2: h2 = relu(ybf @ W2' + bias2')   (bf16 out [N][1024])
  gemm_mfma<false, true, true, false><<<dim3(mb, 8), blk, 0, stream>>>(
      nullptr, ybf, W2T, bias2p, h2, nullptr, N, HC, DHID);

  // GEMM3: z = h2 @ W3 + b3  (f32 out to d_out) + LN3 partial stats
  gemm_mfma<false, false, false, true><<<dim3(mb, 2), blk, 0, stream>>>(
      nullptr, h2, W3T, b3, z, sl3, N, DHID, HC);

  ln_final<<<1, 256, 0, stream>>>(sl3, g3, be3, A3, B3, (double)N * HC);

  ln_apply<<<2048, blk, 0, stream>>>(z, A3, B3, (long)N * HC / 4);
}